// Round 7
// baseline (79.020 us; speedup 1.0000x reference)
//
#include <hip/hip_runtime.h>
#include <stdint.h>

#define BB 32
#define NN 8000
#define MM 256
#define LL (NN + MM)        // 8256
#define NSAMP 512
#define MAXPOS 128
#define T2 1024
#define CH ((LL + T2 - 1) / T2)   // 9
#define SPLIT 4
#define MSUB (MM / SPLIT)   // 64
#define BPT 4               // boxes per thread in match

// forbid fp-contract across this value (exact-path only; matches numpy rounding)
__device__ __forceinline__ void opaquef(float& x) { asm("" : "+v"(x)); }

// exact reference semantics (serial, IEEE div) -- rare fallback
__device__ __noinline__ int serial_argmax(const float4 bx, const float a1,
                                          const float4* s_gt, const float* s_a2)
{
    float qb = -1.0f; int bi = 0;
    for (int m = 0; m < MSUB; ++m) {
        float4 g = s_gt[m];
        float ih = fmaxf(fminf(bx.z, g.z) - fmaxf(bx.x, g.x), 0.0f);
        float iw = fmaxf(fminf(bx.w, g.w) - fmaxf(bx.y, g.y), 0.0f);
        float inter = ih * iw; opaquef(inter);
        float uni = (a1 + s_a2[m]) - inter;
        float q = (uni > 0.0f) ? (inter / uni) : 0.0f;
        if (q > qb) { qb = q; bi = m; }
    }
    return bi;
}

// ---------------- kernel 1: per-(b, 4-box-group, split) argmax over 64 gts -
// Rank by u = inter/(a1+a2): IoU = u/(1-u) is strictly increasing in u, so
// the argmax is identical. Fast path: utilde = inter * v_rcp(s) (<=2^-22 rel
// err incl. fma contraction), key = (u_bits & ~63) | (63-m); running argmax
// is ONE v_max_u32 (truncated-u ties pick smaller m via the index bits).
// Winner is provably the reference's rounded-quotient argmax whenever its
// truncated u beats the runner-up by >= 2 trunc steps (uint gap > 64):
// true-u gap >= ~2^-17 rel then, dwarfing all rounding (2^-22 fast path,
// 2^-23 reference division). Gap <= 1 step -> serial exact redo (~1e-5).
// Zero-inter rows: all keys = 63-m -> argmax m=0, matching the reference for
// invalid boxes/gts (their sim=-1 never wins; all-equal rows keep index 0).
__global__ __launch_bounds__(256) void match_split_kernel(
    const float* __restrict__ boxes, const float* __restrict__ gt,
    uint8_t* __restrict__ pidx)
{
    __shared__ float4 s_gt[MSUB];
    __shared__ float  s_a2[MSUB];
    const int b = blockIdx.y, sp = blockIdx.z, tid = threadIdx.x;
    if (tid < MSUB) {
        float4 v = ((const float4*)(gt + ((size_t)b * MM + sp * MSUB) * 4))[tid];
        s_gt[tid] = v;
        s_a2[tid] = (v.z - v.x) * (v.w - v.y);   // invalid gt (-1,...) -> 0
    }
    __syncthreads();
    const int l0 = blockIdx.x * (256 * BPT) + tid * BPT;
    if (l0 >= LL) return;

    const float4* bb4 = (const float4*)(boxes + (size_t)b * NN * 4);
    const float4* gb4 = (const float4*)(gt + (size_t)b * MM * 4);

    float4 bx[BPT]; float a1[BPT]; bool val[BPT];
    uint32_t best[BPT], best2[BPT];
    #pragma unroll
    for (int j = 0; j < BPT; ++j) {
        const int l = l0 + j;
        val[j] = (l < LL);
        const int lc = val[j] ? l : l0;
        bx[j] = (lc < NN) ? bb4[lc] : gb4[lc - NN];
        a1[j] = (bx[j].z - bx[j].x) * (bx[j].w - bx[j].y);
        best[j] = 0; best2[j] = 0;
    }

    #pragma unroll 8
    for (int m = 0; m < MSUB; ++m) {
        const float4 g = s_gt[m];
        const float a2 = s_a2[m];
        #pragma unroll
        for (int j = 0; j < BPT; ++j) {
            float ih = fmaxf(fminf(bx[j].z, g.z) - fmaxf(bx[j].x, g.x), 0.0f);
            float iw = fmaxf(fminf(bx[j].w, g.w) - fmaxf(bx[j].y, g.y), 0.0f);
            float inter = ih * iw;
            float s = fmaxf(a1[j] + a2, 1e-30f);   // clamp: 0/0 -> 0, not NaN
            float u = inter * __builtin_amdgcn_rcpf(s);
            uint32_t key = (__float_as_uint(u) & 0xFFFFFFC0u) | (uint32_t)(63 - m);
            uint32_t old = best[j];
            best[j]  = max(old, key);
            best2[j] = max(best2[j], min(old, key));
        }
    }

    int lb[BPT]; bool redo[BPT]; bool anyredo = false;
    #pragma unroll
    for (int j = 0; j < BPT; ++j) {
        lb[j] = 63 - (int)(best[j] & 63u);
        const uint32_t qp = best[j] & 0xFFFFFFC0u;
        redo[j] = val[j] && (qp != 0u) &&
                  ((qp - (best2[j] & 0xFFFFFFC0u)) <= 64u);
        anyredo |= redo[j];
    }
    if (__any(anyredo)) {
        #pragma unroll
        for (int j = 0; j < BPT; ++j)
            if (redo[j]) lb[j] = serial_argmax(bx[j], a1[j], s_gt, s_a2);
    }
    #pragma unroll
    for (int j = 0; j < BPT; ++j)
        if (val[j]) pidx[((size_t)b * LL + (l0 + j)) * SPLIT + sp] = (uint8_t)lb[j];
}

// ---------------- kernel 1b: merge 4 split winners, exact rounded q --------
__global__ __launch_bounds__(256) void merge_kernel(
    const float* __restrict__ boxes, const float* __restrict__ gt,
    const uint8_t* __restrict__ pidx, uint16_t* __restrict__ packed)
{
    const int b = blockIdx.y;
    const int l = blockIdx.x * 256 + threadIdx.x;
    if (l >= LL) return;
    float4 bx = (l < NN) ? ((const float4*)(boxes + (size_t)b * NN * 4))[l]
                         : ((const float4*)(gt + (size_t)b * MM * 4))[l - NN];
    int cls, bidx = 0;
    if (fmaxf(fmaxf(bx.x, bx.y), fmaxf(bx.z, bx.w)) < 0.0f) {
        cls = 2;   // all sim == -1 -> invalid, argmax = 0
    } else {
        float a1 = (bx.z - bx.x) * (bx.w - bx.y);
        opaquef(a1);
        float qb = -1.0f;
        const uint32_t pv = *(const uint32_t*)&pidx[((size_t)b * LL + l) * SPLIT];
        #pragma unroll
        for (int sp = 0; sp < SPLIT; ++sp) {
            const int m = sp * MSUB + (int)((pv >> (8 * sp)) & 0xFFu);
            float4 g = ((const float4*)(gt + (size_t)b * MM * 4))[m];
            float a2 = (g.z - g.x) * (g.w - g.y); opaquef(a2);
            float ih = fmaxf(fminf(bx.z, g.z) - fmaxf(bx.x, g.x), 0.0f);
            float iw = fmaxf(fminf(bx.w, g.w) - fmaxf(bx.y, g.y), 0.0f);
            float inter = ih * iw; opaquef(inter);
            float uni = (a1 + a2) - inter;        // numpy op order/rounding
            float q = (uni > 0.0f) ? (inter / uni) : 0.0f;   // exact reference
            if (q > qb) { qb = q; bidx = m; }     // split order = index order
        }
        cls = (qb >= 0.5f) ? 1 : 0;   // searchsorted([0,.5,.5], right)
    }
    packed[(size_t)b * LL + l] = (uint16_t)(cls | (bidx << 2));
}

// ---------------- scans ----------------
// Full-block (16-wave) exclusive scan; wt[15] holds block total afterwards.
__device__ __forceinline__ int block_exscan_fast(int v, int* wt, int tid)
{
    const int lane = tid & 63, w = tid >> 6;
    int x = v;
    #pragma unroll
    for (int off = 1; off < 64; off <<= 1) {
        int y = __shfl_up(x, off);
        if (lane >= off) x += y;
    }
    if (lane == 63) wt[w] = x;
    __syncthreads();
    if (tid < 64) {
        int t = (tid < 16) ? wt[tid] : 0;
        #pragma unroll
        for (int off = 1; off < 16; off <<= 1) {
            int y = __shfl_up(t, off);
            if (tid >= off) t += y;
        }
        if (tid < 16) wt[tid] = t;
    }
    __syncthreads();
    return ((w > 0) ? wt[w - 1] : 0) + x - v;
}

// Segmented exclusive scan: independent segments of 4 waves (256 threads).
__device__ __forceinline__ int block_exscan_seg4(int v, int* wt, int tid)
{
    const int lane = tid & 63, w = tid >> 6;
    int x = v;
    #pragma unroll
    for (int off = 1; off < 64; off <<= 1) {
        int y = __shfl_up(x, off);
        if (lane >= off) x += y;
    }
    if (lane == 63) wt[w] = x;
    __syncthreads();
    if (tid < 16) {
        int t = wt[tid];
        #pragma unroll
        for (int off = 1; off < 4; off <<= 1) {
            int y = __shfl_up(t, off);
            if ((tid & 3) >= off) t += y;
        }
        wt[tid] = t;   // inclusive scan within each 4-wave group
    }
    __syncthreads();
    return (((w & 3) > 0) ? wt[w - 1] : 0) + x - v;
}

// ---------------- kernel 2: per-batch sampling + gather ----------------
// s_pk bit layout: [1:0] cls, [9:2] matched gt idx, [15] sel flag
__global__ __launch_bounds__(T2) void sample_kernel(
    const float* __restrict__ boxes, const float* __restrict__ gt,
    const int* __restrict__ gtc, const float* __restrict__ rnd,
    const uint16_t* __restrict__ packed, float* __restrict__ out)
{
    __shared__ uint32_t s_key[LL];     // 33024 B
    __shared__ uint16_t s_pk[LL];      // 16512 B
    __shared__ int s_hist[512];        // 2048 B
    __shared__ int s_warp[16];
    __shared__ int s_idx[NSAMP];       // 2048 B
    __shared__ int s_sb[8];
    const int b = blockIdx.x, tid = threadIdx.x, lane = tid & 63;
    const float4* bb4 = (const float4*)(boxes + (size_t)b * NN * 4);
    const float4* gb4 = (const float4*)(gt + (size_t)b * MM * 4);

    if (tid == 0) s_sb[0] = 0;
    __syncthreads();

    // load + packed class counts (neg low16 | pos high16)
    int loc = 0;
    for (int l = tid; l < LL; l += T2) {
        s_key[l] = __float_as_uint(rnd[(size_t)b * LL + l]);
        uint16_t p = packed[(size_t)b * LL + l];
        s_pk[l] = p;
        int c = p & 3;
        loc += (c == 0) ? 1 : ((c == 1) ? 0x10000 : 0);
    }
    #pragma unroll
    for (int off = 32; off; off >>= 1) loc += __shfl_xor(loc, off);
    if (lane == 0) atomicAdd(&s_sb[0], loc);
    __syncthreads();
    const int Nn = s_sb[0] & 0xFFFF, P = s_sb[0] >> 16;

    const int posK = (P < MAXPOS) ? P : MAXPOS;
    const int negK = NSAMP - posK;
    const bool negRad = (Nn > negK);
    const bool posRad = (P > MAXPOS);

    // --- fused dual-class radix select (4 rounds over 8-bit digits) ---
    uint32_t prefix0 = 0, prefix1 = 0;
    int rem0 = negK, rem1 = MAXPOS;
    if (negRad || posRad) {
        for (int round = 0; round < 4; ++round) {
            const int shift = 24 - 8 * round;
            if (tid < 512) s_hist[tid] = 0;
            __syncthreads();
            const uint32_t pmask = (round == 0) ? 0u : (0xFFFFFFFFu << (shift + 8));
            for (int l = tid; l < LL; l += T2) {
                const uint32_t k = s_key[l];
                const int c = s_pk[l] & 3;
                bool doit = (c == 0) ? (negRad && ((k & pmask) == prefix0))
                          : (c == 1) ? (posRad && ((k & pmask) == prefix1))
                          : false;
                if (doit) atomicAdd(&s_hist[(c << 8) | ((k >> shift) & 255)], 1);
            }
            __syncthreads();
            // reversed scan within each class segment (suffix sums)
            int h = 0;
            if (tid < 512) h = s_hist[(tid & 0x100) | (255 - (tid & 255))];
            const int above = block_exscan_seg4(h, s_warp, tid);
            if (tid < 512) {
                const int c = tid >> 8;
                const int rem = c ? rem1 : rem0;
                const bool act = c ? posRad : negRad;
                if (act && above < rem && above + h >= rem) {
                    s_sb[4 + c * 2] = 255 - (tid & 255);   // crossing bin
                    s_sb[5 + c * 2] = above;               // strictly-above count
                }
            }
            __syncthreads();
            if (negRad) { prefix0 |= ((uint32_t)s_sb[4]) << shift; rem0 -= s_sb[5]; }
            if (posRad) { prefix1 |= ((uint32_t)s_sb[6]) << shift; rem1 -= s_sb[7]; }
            __syncthreads();
        }
    }
    // unify trivial classes: thr=0, rem=LL selects the whole class
    const uint32_t thr0 = negRad ? prefix0 : 0u;  const int r0 = negRad ? rem0 : LL;
    const uint32_t thr1 = posRad ? prefix1 : 0u;  const int r1 = posRad ? rem1 : LL;

    // --- fused mark pass (tie counts packed: neg low16 | pos high16) ---
    const int lo = tid * CH, hi = (lo + CH < LL) ? (lo + CH) : LL;
    int nt = 0;
    for (int l = lo; l < hi; ++l) {
        const int c = s_pk[l] & 3;
        const uint32_t k = s_key[l];
        if (c == 0) { if (k == thr0) nt += 1; }
        else if (c == 1) { if (k == thr1) nt += 0x10000; }
    }
    const int basep = block_exscan_fast(nt, s_warp, tid);
    int base0 = basep & 0xFFFF, base1 = basep >> 16;
    for (int l = lo; l < hi; ++l) {
        const int c = s_pk[l] & 3;
        if (c > 1) continue;
        const uint32_t k = s_key[l];
        const uint32_t thr = c ? thr1 : thr0;
        bool sel = (k > thr);
        if (k == thr) {
            if (c == 0) { sel = (base0 < r0); ++base0; }
            else        { sel = (base1 < r1); ++base1; }
        }
        if (sel) s_pk[l] |= 0x8000;
    }
    __syncthreads();

    // --- compaction: selected ascending then unselected ascending (packed) ---
    int cnt = 0;
    for (int l = lo; l < hi; ++l) cnt += (s_pk[l] & 0x8000) ? 1 : 0x10000;
    const int pb = block_exscan_fast(cnt, s_warp, tid);
    const int S = s_warp[15] & 0xFFFF;            // total selected
    int bs = pb & 0xFFFF, bu = (pb >> 16) + S;
    for (int l = lo; l < hi; ++l) {
        if (s_pk[l] & 0x8000) { if (bs < NSAMP) s_idx[bs] = l; ++bs; }
        else                  { if (bu < NSAMP) s_idx[bu] = l; ++bu; }
    }
    __syncthreads();

    // --- gather + write all 4 outputs (ints written as float values) ---
    if (tid < NSAMP) {
        const int l = s_idx[tid];
        float4 bx = (l < NN) ? bb4[l] : gb4[l - NN];
        const int p = s_pk[l];
        const int c = p & 3, mi = (p >> 2) & 0xFF;
        const bool bg = (c != 1);          // background = matched_val < 0.5
        float4 gb = make_float4(0.f, 0.f, 0.f, 0.f);
        int cl = 0, si = -1;
        if (!bg) {
            gb = gb4[mi];
            cl = gtc[(size_t)b * MM + mi];
            si = mi;
        }
        const size_t rk = (size_t)b * NSAMP + tid;
        ((float4*)out)[rk] = bx;                                   // rois
        ((float4*)(out + (size_t)BB * NSAMP * 4))[rk] = gb;        // sampled_gt_boxes
        out[(size_t)2 * BB * NSAMP * 4 + rk] = (float)cl;          // classes
        out[(size_t)2 * BB * NSAMP * 4 + (size_t)BB * NSAMP + rk] = (float)si; // indices
    }
}

extern "C" void kernel_launch(void* const* d_in, const int* in_sizes, int n_in,
                              void* d_out, int out_size, void* d_ws, size_t ws_size,
                              hipStream_t stream)
{
    const float* boxes = (const float*)d_in[0];   // [32,8000,4] f32
    const float* gt    = (const float*)d_in[1];   // [32,256,4]  f32
    const int*   gtc   = (const int*)  d_in[2];   // [32,256]    i32
    const float* rnd   = (const float*)d_in[3];   // [32,8256]   f32
    float* out = (float*)d_out;
    uint8_t*  pidx   = (uint8_t*)d_ws;                                     // 1.06 MB
    uint16_t* packed = (uint16_t*)((char*)d_ws + (size_t)BB * LL * SPLIT); // 0.53 MB

    dim3 g1((LL + 256 * BPT - 1) / (256 * BPT), BB, SPLIT);   // 9,32,4
    match_split_kernel<<<g1, 256, 0, stream>>>(boxes, gt, pidx);
    dim3 g2((LL + 255) / 256, BB);
    merge_kernel<<<g2, 256, 0, stream>>>(boxes, gt, pidx, packed);
    sample_kernel<<<BB, T2, 0, stream>>>(boxes, gt, gtc, rnd, packed, out);
}

// Round 8
// 75.489 us; speedup vs baseline: 1.0468x; 1.0468x over previous
//
#include <hip/hip_runtime.h>
#include <stdint.h>

#define BB 32
#define NN 8000
#define MM 256
#define LL (NN + MM)        // 8256
#define NSAMP 512
#define MAXPOS 128
#define T2 1024
#define CH ((LL + T2 - 1) / T2)   // 9
#define SPLIT 4
#define MSUB (MM / SPLIT)   // 64

// forbid fp-contract across this value (exact-path: match numpy rounding)
__device__ __forceinline__ void opaquef(float& x) { asm("" : "+v"(x)); }

// exact reference semantics within one split (serial, IEEE div) -- rare
__device__ __noinline__ int serial_argmax(const float4 bx, const float a1,
                                          const float4* s_gt, const float* s_a2)
{
    float qb = -1.0f; int bi = 0;
    for (int m = 0; m < MSUB; ++m) {
        float4 g = s_gt[m];
        float ih = fmaxf(fminf(bx.z, g.z) - fmaxf(bx.x, g.x), 0.0f);
        float iw = fmaxf(fminf(bx.w, g.w) - fmaxf(bx.y, g.y), 0.0f);
        float inter = ih * iw; opaquef(inter);
        float uni = (a1 + s_a2[m]) - inter;
        float q = (uni > 0.0f) ? (inter / uni) : 0.0f;
        if (q > qb) { qb = q; bi = m; }
    }
    return bi;
}

__device__ __forceinline__ uint32_t approx_key(const float4 bx, float a1,
                                               const float4 g, float a2, int m)
{
    float ih = fmaxf(fminf(bx.z, g.z) - fmaxf(bx.x, g.x), 0.0f);
    float iw = fmaxf(fminf(bx.w, g.w) - fmaxf(bx.y, g.y), 0.0f);
    float inter = ih * iw;
    float s = fmaxf(a1 + a2, 1e-30f);              // 0/0 -> 0, never NaN
    float u = inter * __builtin_amdgcn_rcpf(s);    // <=2^-22 rel err
    return (__float_as_uint(u) & 0xFFFFFFC0u) | (uint32_t)(63 - m);
}

// ---------------- kernel 1: per-(b, box-pair, split) argmax over 64 gts ----
// Rank by u = inter/(a1+a2): IoU = u/(1-u) strictly increasing in u -> same
// argmax. key = (u_bits & ~63) | (63-m): running argmax is ONE v_max_u32,
// truncated-u ties pick smaller m. Winner is provably the reference's
// rounded-quotient argmax when its truncated u beats the runner-up by >= 2
// trunc steps (gap > 64 ulp -> true-u rel gap >= ~2^-17, dwarfing 2^-22 fast
// rounding and 2^-23 reference rounding). Gap <= 1 step -> serial exact redo.
// Zero-inter rows: keys = 63-m -> m=0 wins, matching reference (-1 rows).
// BPT=2 boxes/thread (R6-proven occupancy; R7's BPT=4 collapsed latency
// hiding). Output: u32 key per (l,split) (FUSED) or u8 winner idx.
template<bool FUSED>
__global__ __launch_bounds__(256) void match_split_kernel(
    const float* __restrict__ boxes, const float* __restrict__ gt,
    void* __restrict__ outp)
{
    __shared__ float4 s_gt[MSUB];
    __shared__ float  s_a2[MSUB];
    const int b = blockIdx.y, sp = blockIdx.z, tid = threadIdx.x;
    if (tid < MSUB) {
        float4 v = ((const float4*)(gt + ((size_t)b * MM + sp * MSUB) * 4))[tid];
        s_gt[tid] = v;
        s_a2[tid] = (v.z - v.x) * (v.w - v.y);   // invalid gt (-1,...) -> 0
    }
    __syncthreads();
    const int l0 = blockIdx.x * 512 + tid * 2;
    if (l0 >= LL) return;
    const int l1 = l0 + 1;
    const bool v1 = (l1 < LL);
    const int l1c = v1 ? l1 : l0;

    const float4* bb4 = (const float4*)(boxes + (size_t)b * NN * 4);
    const float4* gb4 = (const float4*)(gt + (size_t)b * MM * 4);
    float4 bx0 = (l0 < NN) ? bb4[l0] : gb4[l0 - NN];
    float4 bx1 = (l1c < NN) ? bb4[l1c] : gb4[l1c - NN];
    float a10 = (bx0.z - bx0.x) * (bx0.w - bx0.y); opaquef(a10);
    float a11 = (bx1.z - bx1.x) * (bx1.w - bx1.y); opaquef(a11);

    uint32_t best0 = 0, sec0 = 0, best1 = 0, sec1 = 0;
    #pragma unroll 8
    for (int m = 0; m < MSUB; ++m) {
        const float4 g = s_gt[m];
        const float a2 = s_a2[m];
        {
            uint32_t key = approx_key(bx0, a10, g, a2, m);
            uint32_t old = best0;
            best0 = max(old, key);
            sec0  = max(sec0, min(old, key));
        }
        {
            uint32_t key = approx_key(bx1, a11, g, a2, m);
            uint32_t old = best1;
            best1 = max(old, key);
            sec1  = max(sec1, min(old, key));
        }
    }

    bool redo0 = ((best0 & ~63u) != 0u) &&
                 (((best0 & ~63u) - (sec0 & ~63u)) <= 64u);
    bool redo1 = v1 && ((best1 & ~63u) != 0u) &&
                 (((best1 & ~63u) - (sec1 & ~63u)) <= 64u);
    if (__any(redo0 || redo1)) {
        if (redo0) {
            int mW = serial_argmax(bx0, a10, s_gt, s_a2);
            best0 = approx_key(bx0, a10, s_gt[mW], s_a2[mW], mW);
        }
        if (redo1) {
            int mW = serial_argmax(bx1, a11, s_gt, s_a2);
            best1 = approx_key(bx1, a11, s_gt[mW], s_a2[mW], mW);
        }
    }
    if (FUSED) {
        uint32_t* keys = (uint32_t*)outp;
        keys[((size_t)b * LL + l0) * SPLIT + sp] = best0;
        if (v1) keys[((size_t)b * LL + l1) * SPLIT + sp] = best1;
    } else {
        uint8_t* pidx = (uint8_t*)outp;
        pidx[((size_t)b * LL + l0) * SPLIT + sp] = (uint8_t)(63 - (best0 & 63u));
        if (v1) pidx[((size_t)b * LL + l1) * SPLIT + sp] = (uint8_t)(63 - (best1 & 63u));
    }
}

// ---------------- kernel 1b (fallback only): merge 4 split winners ---------
__global__ __launch_bounds__(256) void merge_kernel(
    const float* __restrict__ boxes, const float* __restrict__ gt,
    const uint8_t* __restrict__ pidx, uint16_t* __restrict__ packed)
{
    const int b = blockIdx.y;
    const int l = blockIdx.x * 256 + threadIdx.x;
    if (l >= LL) return;
    float4 bx = (l < NN) ? ((const float4*)(boxes + (size_t)b * NN * 4))[l]
                         : ((const float4*)(gt + (size_t)b * MM * 4))[l - NN];
    int cls, bidx = 0;
    if (fmaxf(fmaxf(bx.x, bx.y), fmaxf(bx.z, bx.w)) < 0.0f) {
        cls = 2;
    } else {
        float a1 = (bx.z - bx.x) * (bx.w - bx.y); opaquef(a1);
        float qb = -1.0f;
        const uint32_t pv = *(const uint32_t*)&pidx[((size_t)b * LL + l) * SPLIT];
        #pragma unroll
        for (int sp = 0; sp < SPLIT; ++sp) {
            const int m = sp * MSUB + (int)((pv >> (8 * sp)) & 0xFFu);
            float4 g = ((const float4*)(gt + (size_t)b * MM * 4))[m];
            float a2 = (g.z - g.x) * (g.w - g.y); opaquef(a2);
            float ih = fmaxf(fminf(bx.z, g.z) - fmaxf(bx.x, g.x), 0.0f);
            float iw = fmaxf(fminf(bx.w, g.w) - fmaxf(bx.y, g.y), 0.0f);
            float inter = ih * iw; opaquef(inter);
            float uni = (a1 + a2) - inter;
            float q = (uni > 0.0f) ? (inter / uni) : 0.0f;
            if (q > qb) { qb = q; bidx = m; }
        }
        cls = (qb >= 0.5f) ? 1 : 0;
    }
    packed[(size_t)b * LL + l] = (uint16_t)(cls | (bidx << 2));
}

// ---------------- scans ----------------
__device__ __forceinline__ int block_exscan_fast(int v, int* wt, int tid)
{
    const int lane = tid & 63, w = tid >> 6;
    int x = v;
    #pragma unroll
    for (int off = 1; off < 64; off <<= 1) {
        int y = __shfl_up(x, off);
        if (lane >= off) x += y;
    }
    if (lane == 63) wt[w] = x;
    __syncthreads();
    if (tid < 64) {
        int t = (tid < 16) ? wt[tid] : 0;
        #pragma unroll
        for (int off = 1; off < 16; off <<= 1) {
            int y = __shfl_up(t, off);
            if (tid >= off) t += y;
        }
        if (tid < 16) wt[tid] = t;
    }
    __syncthreads();
    return ((w > 0) ? wt[w - 1] : 0) + x - v;
}

__device__ __forceinline__ int block_exscan_seg4(int v, int* wt, int tid)
{
    const int lane = tid & 63, w = tid >> 6;
    int x = v;
    #pragma unroll
    for (int off = 1; off < 64; off <<= 1) {
        int y = __shfl_up(x, off);
        if (lane >= off) x += y;
    }
    if (lane == 63) wt[w] = x;
    __syncthreads();
    if (tid < 16) {
        int t = wt[tid];
        #pragma unroll
        for (int off = 1; off < 4; off <<= 1) {
            int y = __shfl_up(t, off);
            if ((tid & 3) >= off) t += y;
        }
        wt[tid] = t;
    }
    __syncthreads();
    return (((w & 3) > 0) ? wt[w - 1] : 0) + x - v;
}

// ---------------- kernel 2: (merge) + per-batch sampling + gather ----------
// s_pk bit layout: [1:0] cls, [9:2] matched gt idx, [15] sel flag
template<bool FUSED>
__global__ __launch_bounds__(T2) void sample_kernel(
    const float* __restrict__ boxes, const float* __restrict__ gt,
    const int* __restrict__ gtc, const float* __restrict__ rnd,
    const void* __restrict__ matchp, float* __restrict__ out)
{
    __shared__ uint32_t s_key[LL];
    __shared__ uint16_t s_pk[LL];
    __shared__ int s_hist[512];
    __shared__ int s_warp[16];
    __shared__ int s_idx[NSAMP];
    __shared__ int s_sb[8];
    const int b = blockIdx.x, tid = threadIdx.x, lane = tid & 63;
    const float4* bb4 = (const float4*)(boxes + (size_t)b * NN * 4);
    const float4* gb4 = (const float4*)(gt + (size_t)b * MM * 4);

    if (tid == 0) s_sb[0] = 0;
    __syncthreads();

    // load keys + (FUSED: cross-split winner + one exact IoU for cls) +
    // packed class counts (neg low16 | pos high16)
    int loc = 0;
    for (int l = tid; l < LL; l += T2) {
        s_key[l] = __float_as_uint(rnd[(size_t)b * LL + l]);
        int cls, midx;
        if (FUSED) {
            const uint4 kv = ((const uint4*)matchp)[(size_t)b * LL + l];
            float4 bx = (l < NN) ? bb4[l] : gb4[l - NN];
            if (fmaxf(fmaxf(bx.x, bx.y), fmaxf(bx.z, bx.w)) < 0.0f) {
                cls = 2; midx = 0;   // all sim == -1 -> invalid, argmax = 0
            } else {
                // winner across splits: strict > keeps the LOWER split on
                // equal keys (within-split ties already resolved exactly)
                uint32_t best = kv.x; int bsp = 0;
                if (kv.y > best) { best = kv.y; bsp = 1; }
                if (kv.z > best) { best = kv.z; bsp = 2; }
                if (kv.w > best) { best = kv.w; bsp = 3; }
                const uint32_t bt = best & ~63u;
                const uint32_t s0 = (bsp == 0) ? 0u : (kv.x & ~63u);
                const uint32_t s1 = (bsp == 1) ? 0u : (kv.y & ~63u);
                const uint32_t s2 = (bsp == 2) ? 0u : (kv.z & ~63u);
                const uint32_t s3 = (bsp == 3) ? 0u : (kv.w & ~63u);
                const uint32_t sec = max(max(s0, s1), max(s2, s3));
                float a1 = (bx.z - bx.x) * (bx.w - bx.y); opaquef(a1);
                if ((bt != 0u) && (bt - sec) <= 64u) {
                    // ambiguous across splits: exact 4-way, first-argmax by
                    // global index (split ascending, strict >)
                    float qb = -1.0f; midx = 0;
                    #pragma unroll
                    for (int sp = 0; sp < SPLIT; ++sp) {
                        const uint32_t k = (sp == 0) ? kv.x : (sp == 1) ? kv.y
                                         : (sp == 2) ? kv.z : kv.w;
                        const int m = sp * MSUB + (63 - (int)(k & 63u));
                        float4 g = gb4[m];
                        float a2 = (g.z - g.x) * (g.w - g.y); opaquef(a2);
                        float ih = fmaxf(fminf(bx.z, g.z) - fmaxf(bx.x, g.x), 0.0f);
                        float iw = fmaxf(fminf(bx.w, g.w) - fmaxf(bx.y, g.y), 0.0f);
                        float inter = ih * iw; opaquef(inter);
                        float uni = (a1 + a2) - inter;
                        float q = (uni > 0.0f) ? (inter / uni) : 0.0f;
                        if (q > qb) { qb = q; midx = m; }
                    }
                    cls = (qb >= 0.5f) ? 1 : 0;
                } else {
                    midx = bsp * MSUB + (63 - (int)(best & 63u));
                    float4 g = gb4[midx];
                    float a2 = (g.z - g.x) * (g.w - g.y); opaquef(a2);
                    float ih = fmaxf(fminf(bx.z, g.z) - fmaxf(bx.x, g.x), 0.0f);
                    float iw = fmaxf(fminf(bx.w, g.w) - fmaxf(bx.y, g.y), 0.0f);
                    float inter = ih * iw; opaquef(inter);
                    float uni = (a1 + a2) - inter;   // numpy op order/rounding
                    float q = (uni > 0.0f) ? (inter / uni) : 0.0f;  // exact ref
                    cls = (q >= 0.5f) ? 1 : 0;       // searchsorted right
                }
            }
        } else {
            const uint16_t p = ((const uint16_t*)matchp)[(size_t)b * LL + l];
            cls = p & 3; midx = (p >> 2) & 0xFF;
        }
        s_pk[l] = (uint16_t)(cls | (midx << 2));
        loc += (cls == 0) ? 1 : ((cls == 1) ? 0x10000 : 0);
    }
    #pragma unroll
    for (int off = 32; off; off >>= 1) loc += __shfl_xor(loc, off);
    if (lane == 0) atomicAdd(&s_sb[0], loc);
    __syncthreads();
    const int Nn = s_sb[0] & 0xFFFF, P = s_sb[0] >> 16;

    const int posK = (P < MAXPOS) ? P : MAXPOS;
    const int negK = NSAMP - posK;
    const bool negRad = (Nn > negK);
    const bool posRad = (P > MAXPOS);

    // --- fused dual-class radix select (4 rounds over 8-bit digits) ---
    uint32_t prefix0 = 0, prefix1 = 0;
    int rem0 = negK, rem1 = MAXPOS;
    if (negRad || posRad) {
        for (int round = 0; round < 4; ++round) {
            const int shift = 24 - 8 * round;
            if (tid < 512) s_hist[tid] = 0;
            __syncthreads();
            const uint32_t pmask = (round == 0) ? 0u : (0xFFFFFFFFu << (shift + 8));
            for (int l = tid; l < LL; l += T2) {
                const uint32_t k = s_key[l];
                const int c = s_pk[l] & 3;
                bool doit = (c == 0) ? (negRad && ((k & pmask) == prefix0))
                          : (c == 1) ? (posRad && ((k & pmask) == prefix1))
                          : false;
                if (doit) atomicAdd(&s_hist[(c << 8) | ((k >> shift) & 255)], 1);
            }
            __syncthreads();
            int h = 0;
            if (tid < 512) h = s_hist[(tid & 0x100) | (255 - (tid & 255))];
            const int above = block_exscan_seg4(h, s_warp, tid);
            if (tid < 512) {
                const int c = tid >> 8;
                const int rem = c ? rem1 : rem0;
                const bool act = c ? posRad : negRad;
                if (act && above < rem && above + h >= rem) {
                    s_sb[4 + c * 2] = 255 - (tid & 255);
                    s_sb[5 + c * 2] = above;
                }
            }
            __syncthreads();
            if (negRad) { prefix0 |= ((uint32_t)s_sb[4]) << shift; rem0 -= s_sb[5]; }
            if (posRad) { prefix1 |= ((uint32_t)s_sb[6]) << shift; rem1 -= s_sb[7]; }
            __syncthreads();
        }
    }
    const uint32_t thr0 = negRad ? prefix0 : 0u;  const int r0 = negRad ? rem0 : LL;
    const uint32_t thr1 = posRad ? prefix1 : 0u;  const int r1 = posRad ? rem1 : LL;

    // --- fused mark pass (tie counts packed: neg low16 | pos high16) ---
    const int lo = tid * CH, hi = (lo + CH < LL) ? (lo + CH) : LL;
    int nt = 0;
    for (int l = lo; l < hi; ++l) {
        const int c = s_pk[l] & 3;
        const uint32_t k = s_key[l];
        if (c == 0) { if (k == thr0) nt += 1; }
        else if (c == 1) { if (k == thr1) nt += 0x10000; }
    }
    const int basep = block_exscan_fast(nt, s_warp, tid);
    int base0 = basep & 0xFFFF, base1 = basep >> 16;
    for (int l = lo; l < hi; ++l) {
        const int c = s_pk[l] & 3;
        if (c > 1) continue;
        const uint32_t k = s_key[l];
        const uint32_t thr = c ? thr1 : thr0;
        bool sel = (k > thr);
        if (k == thr) {
            if (c == 0) { sel = (base0 < r0); ++base0; }
            else        { sel = (base1 < r1); ++base1; }
        }
        if (sel) s_pk[l] |= 0x8000;
    }
    __syncthreads();

    // --- compaction: selected ascending then unselected ascending ---
    int cnt = 0;
    for (int l = lo; l < hi; ++l) cnt += (s_pk[l] & 0x8000) ? 1 : 0x10000;
    const int pb = block_exscan_fast(cnt, s_warp, tid);
    const int S = s_warp[15] & 0xFFFF;
    int bs = pb & 0xFFFF, bu = (pb >> 16) + S;
    for (int l = lo; l < hi; ++l) {
        if (s_pk[l] & 0x8000) { if (bs < NSAMP) s_idx[bs] = l; ++bs; }
        else                  { if (bu < NSAMP) s_idx[bu] = l; ++bu; }
    }
    __syncthreads();

    // --- gather + write all 4 outputs (ints written as float values) ---
    if (tid < NSAMP) {
        const int l = s_idx[tid];
        float4 bx = (l < NN) ? bb4[l] : gb4[l - NN];
        const int p = s_pk[l];
        const int c = p & 3, mi = (p >> 2) & 0xFF;
        const bool bg = (c != 1);          // background = matched_val < 0.5
        float4 gb = make_float4(0.f, 0.f, 0.f, 0.f);
        int cl = 0, si = -1;
        if (!bg) {
            gb = gb4[mi];
            cl = gtc[(size_t)b * MM + mi];
            si = mi;
        }
        const size_t rk = (size_t)b * NSAMP + tid;
        ((float4*)out)[rk] = bx;                                   // rois
        ((float4*)(out + (size_t)BB * NSAMP * 4))[rk] = gb;        // sampled_gt_boxes
        out[(size_t)2 * BB * NSAMP * 4 + rk] = (float)cl;          // classes
        out[(size_t)2 * BB * NSAMP * 4 + (size_t)BB * NSAMP + rk] = (float)si; // indices
    }
}

extern "C" void kernel_launch(void* const* d_in, const int* in_sizes, int n_in,
                              void* d_out, int out_size, void* d_ws, size_t ws_size,
                              hipStream_t stream)
{
    const float* boxes = (const float*)d_in[0];   // [32,8000,4] f32
    const float* gt    = (const float*)d_in[1];   // [32,256,4]  f32
    const int*   gtc   = (const int*)  d_in[2];   // [32,256]    i32
    const float* rnd   = (const float*)d_in[3];   // [32,8256]   f32
    float* out = (float*)d_out;

    dim3 g1((LL + 511) / 512, BB, SPLIT);   // 17,32,4 = 2176 blocks (R6-proven)
    const size_t need = (size_t)BB * LL * SPLIT * sizeof(uint32_t);  // 4.22 MB
    if (ws_size >= need) {
        match_split_kernel<true><<<g1, 256, 0, stream>>>(boxes, gt, d_ws);
        sample_kernel<true><<<BB, T2, 0, stream>>>(boxes, gt, gtc, rnd, d_ws, out);
    } else {
        uint8_t*  pidx   = (uint8_t*)d_ws;                                     // 1.06 MB
        uint16_t* packed = (uint16_t*)((char*)d_ws + (size_t)BB * LL * SPLIT); // 0.53 MB
        match_split_kernel<false><<<g1, 256, 0, stream>>>(boxes, gt, pidx);
        dim3 g2((LL + 255) / 256, BB);
        merge_kernel<<<g2, 256, 0, stream>>>(boxes, gt, pidx, packed);
        sample_kernel<false><<<BB, T2, 0, stream>>>(boxes, gt, gtc, rnd, packed, out);
    }
}

// Round 9
// 70.966 us; speedup vs baseline: 1.1135x; 1.0637x over previous
//
#include <hip/hip_runtime.h>
#include <stdint.h>

#define BB 32
#define NN 8000
#define MM 256
#define LL (NN + MM)        // 8256
#define NSAMP 512
#define MAXPOS 128
#define T2 1024
#define CH ((LL + T2 - 1) / T2)   // 9
#define SPLIT 4
#define MSUB (MM / SPLIT)   // 64

// forbid fp-contract across this value (exact-path: match numpy rounding)
__device__ __forceinline__ void opaquef(float& x) { asm("" : "+v"(x)); }

__device__ __forceinline__ uint32_t approx_key(const float4 bx, float a1,
                                               const float4 g, float a2,
                                               uint32_t klo)
{
    float ih = fmaxf(fminf(bx.z, g.z) - fmaxf(bx.x, g.x), 0.0f);
    float iw = fmaxf(fminf(bx.w, g.w) - fmaxf(bx.y, g.y), 0.0f);
    float inter = ih * iw;
    float s = fmaxf(a1 + a2, 1e-30f);              // 0/0 -> 0, never NaN
    float u = inter * __builtin_amdgcn_rcpf(s);    // <=2^-22 rel err
    return (__float_as_uint(u) & 0xFFFFFFC0u) | klo;
}

// exact reference semantics over the compacted valid-gt list (rare fallback)
__device__ __noinline__ int serial_argmax(const float4 bx, const float a1,
                                          const float4* s_gt, const float* s_a2,
                                          int nv)
{
    float qb = -1.0f; int bi = 0;
    for (int m = 0; m < nv; ++m) {
        float4 g = s_gt[m];
        float ih = fmaxf(fminf(bx.z, g.z) - fmaxf(bx.x, g.x), 0.0f);
        float iw = fmaxf(fminf(bx.w, g.w) - fmaxf(bx.y, g.y), 0.0f);
        float inter = ih * iw; opaquef(inter);
        float uni = (a1 + s_a2[m]) - inter;
        float q = (uni > 0.0f) ? (inter / uni) : 0.0f;
        if (q > qb) { qb = q; bi = m; }
    }
    return bi;    // compacted index (ascending original order preserved)
}

// ---------------- kernel 1: per-(b, box-pair, split) argmax over valid gts -
// Rank by u = inter/(a1+a2): IoU = u/(1-u) strictly increasing in u -> same
// argmax. key = (u_bits & ~63) | (63-m): running argmax is ONE v_max_u32,
// truncated-u ties pick smaller m. Guarantee as R6-R8 (gap > 64 ulp ->
// rounded-quotient order provably identical; <= 64 -> exact serial redo).
// NEW: valid gts are COMPACTED into LDS via wave ballot; the m-loop runs only
// over nv valid entries. Invalid gts satisfy inter==0 for every box (their
// coords are all -1, any box clamp gives ih<=0), so they can never win and
// their zero-keys are dominated by (or tie-equivalent to) valid zero-keys;
// all q<0.5 rows are background-nulled downstream, so outputs are identical.
__global__ __launch_bounds__(256) void match_split_kernel(
    const float* __restrict__ boxes, const float* __restrict__ gt,
    uint32_t* __restrict__ keys)
{
    __shared__ float4 s_gt[MSUB];
    __shared__ float  s_a2[MSUB];
    __shared__ uint32_t s_klo[MSUB];
    __shared__ int s_nv;
    const int b = blockIdx.y, sp = blockIdx.z, tid = threadIdx.x;
    if (tid < MSUB) {   // tid 0..63 == wave 0 exactly
        float4 v = ((const float4*)(gt + ((size_t)b * MM + sp * MSUB) * 4))[tid];
        bool valid = !(fmaxf(fmaxf(v.x, v.y), fmaxf(v.z, v.w)) < 0.0f);
        uint64_t mk = __ballot(valid);
        int pos = __popcll(mk & ((1ull << tid) - 1));
        if (valid) {
            s_gt[pos] = v;
            s_a2[pos] = (v.z - v.x) * (v.w - v.y);
            s_klo[pos] = (uint32_t)(63 - tid);
        }
        if (tid == 0) s_nv = (int)__popcll(mk);
    }
    __syncthreads();
    const int l0 = blockIdx.x * 512 + tid * 2;
    if (l0 >= LL) return;
    const int l1 = l0 + 1;
    const bool v1 = (l1 < LL);
    const int l1c = v1 ? l1 : l0;
    const int nv = s_nv;

    const float4* bb4 = (const float4*)(boxes + (size_t)b * NN * 4);
    const float4* gb4 = (const float4*)(gt + (size_t)b * MM * 4);
    float4 bx0 = (l0 < NN) ? bb4[l0] : gb4[l0 - NN];
    float4 bx1 = (l1c < NN) ? bb4[l1c] : gb4[l1c - NN];
    float a10 = (bx0.z - bx0.x) * (bx0.w - bx0.y); opaquef(a10);
    float a11 = (bx1.z - bx1.x) * (bx1.w - bx1.y); opaquef(a11);

    uint32_t best0 = 0, sec0 = 0, best1 = 0, sec1 = 0;
    #pragma unroll 4
    for (int m = 0; m < nv; ++m) {
        const float4 g = s_gt[m];
        const float a2 = s_a2[m];
        const uint32_t klo = s_klo[m];
        {
            uint32_t key = approx_key(bx0, a10, g, a2, klo);
            uint32_t old = best0;
            best0 = max(old, key);
            sec0  = max(sec0, min(old, key));
        }
        {
            uint32_t key = approx_key(bx1, a11, g, a2, klo);
            uint32_t old = best1;
            best1 = max(old, key);
            sec1  = max(sec1, min(old, key));
        }
    }

    bool redo0 = ((best0 & ~63u) != 0u) &&
                 (((best0 & ~63u) - (sec0 & ~63u)) <= 64u);
    bool redo1 = v1 && ((best1 & ~63u) != 0u) &&
                 (((best1 & ~63u) - (sec1 & ~63u)) <= 64u);
    if (__any(redo0 || redo1)) {
        if (redo0) {
            int w = serial_argmax(bx0, a10, s_gt, s_a2, nv);
            best0 = approx_key(bx0, a10, s_gt[w], s_a2[w], s_klo[w]);
        }
        if (redo1) {
            int w = serial_argmax(bx1, a11, s_gt, s_a2, nv);
            best1 = approx_key(bx1, a11, s_gt[w], s_a2[w], s_klo[w]);
        }
    }
    keys[((size_t)b * LL + l0) * SPLIT + sp] = best0;
    if (v1) keys[((size_t)b * LL + l1) * SPLIT + sp] = best1;
}

// ---------------- kernel 1b: cross-split winner + classify (1056 blocks) ---
// Reads the 4 split keys, picks the winner with 3 uint max (strict >, lower
// split keeps on tie). If the winner's truncated-u beats the other splits'
// by > 64 ulp, ONE exact reference IoU+div gives matched_val; else exact
// 4-way re-merge (first-argmax by global index). Writes the u16 cls|midx
// IN-PLACE at the head of this l's own 16-byte key slot (same-thread
// read-then-write; no other thread touches the slot).
__global__ __launch_bounds__(256) void merge2_kernel(
    const float* __restrict__ boxes, const float* __restrict__ gt,
    uint32_t* __restrict__ keys)
{
    const int b = blockIdx.y;
    const int l = blockIdx.x * 256 + threadIdx.x;
    if (l >= LL) return;
    const float4* bb4 = (const float4*)(boxes + (size_t)b * NN * 4);
    const float4* gb4 = (const float4*)(gt + (size_t)b * MM * 4);
    const uint4 kv = ((const uint4*)keys)[(size_t)b * LL + l];
    float4 bx = (l < NN) ? bb4[l] : gb4[l - NN];
    int cls, midx = 0;
    if (fmaxf(fmaxf(bx.x, bx.y), fmaxf(bx.z, bx.w)) < 0.0f) {
        cls = 2;   // invalid box: all sim == -1 -> invalid, argmax = 0
    } else {
        uint32_t best = kv.x; int bsp = 0;
        if (kv.y > best) { best = kv.y; bsp = 1; }
        if (kv.z > best) { best = kv.z; bsp = 2; }
        if (kv.w > best) { best = kv.w; bsp = 3; }
        const uint32_t bt = best & ~63u;
        const uint32_t s0 = (bsp == 0) ? 0u : (kv.x & ~63u);
        const uint32_t s1 = (bsp == 1) ? 0u : (kv.y & ~63u);
        const uint32_t s2 = (bsp == 2) ? 0u : (kv.z & ~63u);
        const uint32_t s3 = (bsp == 3) ? 0u : (kv.w & ~63u);
        const uint32_t sec = max(max(s0, s1), max(s2, s3));
        float a1 = (bx.z - bx.x) * (bx.w - bx.y); opaquef(a1);
        if ((bt != 0u) && (bt - sec) <= 64u) {
            // ambiguous across splits: exact 4-way, split ascending, strict >
            float qb = -1.0f; midx = 0;
            #pragma unroll
            for (int sp = 0; sp < SPLIT; ++sp) {
                const uint32_t k = (sp == 0) ? kv.x : (sp == 1) ? kv.y
                                 : (sp == 2) ? kv.z : kv.w;
                const int m = sp * MSUB + (63 - (int)(k & 63u));
                float4 g = gb4[m];
                float a2 = (g.z - g.x) * (g.w - g.y); opaquef(a2);
                float ih = fmaxf(fminf(bx.z, g.z) - fmaxf(bx.x, g.x), 0.0f);
                float iw = fmaxf(fminf(bx.w, g.w) - fmaxf(bx.y, g.y), 0.0f);
                float inter = ih * iw; opaquef(inter);
                float uni = (a1 + a2) - inter;
                float q = (uni > 0.0f) ? (inter / uni) : 0.0f;
                if (q > qb) { qb = q; midx = m; }
            }
            cls = (qb >= 0.5f) ? 1 : 0;
        } else {
            midx = bsp * MSUB + (63 - (int)(best & 63u));
            float4 g = gb4[midx];
            float a2 = (g.z - g.x) * (g.w - g.y); opaquef(a2);
            float ih = fmaxf(fminf(bx.z, g.z) - fmaxf(bx.x, g.x), 0.0f);
            float iw = fmaxf(fminf(bx.w, g.w) - fmaxf(bx.y, g.y), 0.0f);
            float inter = ih * iw; opaquef(inter);
            float uni = (a1 + a2) - inter;     // numpy op order/rounding
            float q = (uni > 0.0f) ? (inter / uni) : 0.0f;   // exact reference
            cls = (q >= 0.5f) ? 1 : 0;         // searchsorted([0,.5,.5], right)
        }
    }
    ((uint16_t*)keys)[((size_t)b * LL + l) * 8] = (uint16_t)(cls | (midx << 2));
}

// ---------------- scans ----------------
__device__ __forceinline__ int block_exscan_fast(int v, int* wt, int tid)
{
    const int lane = tid & 63, w = tid >> 6;
    int x = v;
    #pragma unroll
    for (int off = 1; off < 64; off <<= 1) {
        int y = __shfl_up(x, off);
        if (lane >= off) x += y;
    }
    if (lane == 63) wt[w] = x;
    __syncthreads();
    if (tid < 64) {
        int t = (tid < 16) ? wt[tid] : 0;
        #pragma unroll
        for (int off = 1; off < 16; off <<= 1) {
            int y = __shfl_up(t, off);
            if (tid >= off) t += y;
        }
        if (tid < 16) wt[tid] = t;
    }
    __syncthreads();
    return ((w > 0) ? wt[w - 1] : 0) + x - v;
}

__device__ __forceinline__ int block_exscan_seg4(int v, int* wt, int tid)
{
    const int lane = tid & 63, w = tid >> 6;
    int x = v;
    #pragma unroll
    for (int off = 1; off < 64; off <<= 1) {
        int y = __shfl_up(x, off);
        if (lane >= off) x += y;
    }
    if (lane == 63) wt[w] = x;
    __syncthreads();
    if (tid < 16) {
        int t = wt[tid];
        #pragma unroll
        for (int off = 1; off < 4; off <<= 1) {
            int y = __shfl_up(t, off);
            if ((tid & 3) >= off) t += y;
        }
        wt[tid] = t;
    }
    __syncthreads();
    return (((w & 3) > 0) ? wt[w - 1] : 0) + x - v;
}

// ---------------- kernel 2: per-batch sampling + gather (lean) -------------
// s_pk bit layout: [1:0] cls, [9:2] matched gt idx, [15] sel flag
__global__ __launch_bounds__(T2) void sample_kernel(
    const float* __restrict__ boxes, const float* __restrict__ gt,
    const int* __restrict__ gtc, const float* __restrict__ rnd,
    const uint32_t* __restrict__ keys, float* __restrict__ out)
{
    __shared__ uint32_t s_key[LL];
    __shared__ uint16_t s_pk[LL];
    __shared__ int s_hist[512];
    __shared__ int s_warp[16];
    __shared__ int s_idx[NSAMP];
    __shared__ int s_sb[8];
    const int b = blockIdx.x, tid = threadIdx.x, lane = tid & 63;
    const float4* bb4 = (const float4*)(boxes + (size_t)b * NN * 4);
    const float4* gb4 = (const float4*)(gt + (size_t)b * MM * 4);

    if (tid == 0) s_sb[0] = 0;
    __syncthreads();

    // load + packed class counts (neg low16 | pos high16)
    int loc = 0;
    for (int l = tid; l < LL; l += T2) {
        s_key[l] = __float_as_uint(rnd[(size_t)b * LL + l]);
        uint16_t p = ((const uint16_t*)keys)[((size_t)b * LL + l) * 8];
        s_pk[l] = p;
        int c = p & 3;
        loc += (c == 0) ? 1 : ((c == 1) ? 0x10000 : 0);
    }
    #pragma unroll
    for (int off = 32; off; off >>= 1) loc += __shfl_xor(loc, off);
    if (lane == 0) atomicAdd(&s_sb[0], loc);
    __syncthreads();
    const int Nn = s_sb[0] & 0xFFFF, P = s_sb[0] >> 16;

    const int posK = (P < MAXPOS) ? P : MAXPOS;
    const int negK = NSAMP - posK;
    const bool negRad = (Nn > negK);
    const bool posRad = (P > MAXPOS);

    // --- fused dual-class radix select (4 rounds over 8-bit digits) ---
    uint32_t prefix0 = 0, prefix1 = 0;
    int rem0 = negK, rem1 = MAXPOS;
    if (negRad || posRad) {
        for (int round = 0; round < 4; ++round) {
            const int shift = 24 - 8 * round;
            if (tid < 512) s_hist[tid] = 0;
            __syncthreads();
            const uint32_t pmask = (round == 0) ? 0u : (0xFFFFFFFFu << (shift + 8));
            for (int l = tid; l < LL; l += T2) {
                const uint32_t k = s_key[l];
                const int c = s_pk[l] & 3;
                bool doit = (c == 0) ? (negRad && ((k & pmask) == prefix0))
                          : (c == 1) ? (posRad && ((k & pmask) == prefix1))
                          : false;
                if (doit) atomicAdd(&s_hist[(c << 8) | ((k >> shift) & 255)], 1);
            }
            __syncthreads();
            int h = 0;
            if (tid < 512) h = s_hist[(tid & 0x100) | (255 - (tid & 255))];
            const int above = block_exscan_seg4(h, s_warp, tid);
            if (tid < 512) {
                const int c = tid >> 8;
                const int rem = c ? rem1 : rem0;
                const bool act = c ? posRad : negRad;
                if (act && above < rem && above + h >= rem) {
                    s_sb[4 + c * 2] = 255 - (tid & 255);
                    s_sb[5 + c * 2] = above;
                }
            }
            __syncthreads();
            if (negRad) { prefix0 |= ((uint32_t)s_sb[4]) << shift; rem0 -= s_sb[5]; }
            if (posRad) { prefix1 |= ((uint32_t)s_sb[6]) << shift; rem1 -= s_sb[7]; }
            __syncthreads();
        }
    }
    const uint32_t thr0 = negRad ? prefix0 : 0u;  const int r0 = negRad ? rem0 : LL;
    const uint32_t thr1 = posRad ? prefix1 : 0u;  const int r1 = posRad ? rem1 : LL;

    // --- fused mark pass (tie counts packed: neg low16 | pos high16) ---
    const int lo = tid * CH, hi = (lo + CH < LL) ? (lo + CH) : LL;
    int nt = 0;
    for (int l = lo; l < hi; ++l) {
        const int c = s_pk[l] & 3;
        const uint32_t k = s_key[l];
        if (c == 0) { if (k == thr0) nt += 1; }
        else if (c == 1) { if (k == thr1) nt += 0x10000; }
    }
    const int basep = block_exscan_fast(nt, s_warp, tid);
    int base0 = basep & 0xFFFF, base1 = basep >> 16;
    for (int l = lo; l < hi; ++l) {
        const int c = s_pk[l] & 3;
        if (c > 1) continue;
        const uint32_t k = s_key[l];
        const uint32_t thr = c ? thr1 : thr0;
        bool sel = (k > thr);
        if (k == thr) {
            if (c == 0) { sel = (base0 < r0); ++base0; }
            else        { sel = (base1 < r1); ++base1; }
        }
        if (sel) s_pk[l] |= 0x8000;
    }
    __syncthreads();

    // --- compaction: selected ascending then unselected ascending ---
    int cnt = 0;
    for (int l = lo; l < hi; ++l) cnt += (s_pk[l] & 0x8000) ? 1 : 0x10000;
    const int pb = block_exscan_fast(cnt, s_warp, tid);
    const int S = s_warp[15] & 0xFFFF;
    int bs = pb & 0xFFFF, bu = (pb >> 16) + S;
    for (int l = lo; l < hi; ++l) {
        if (s_pk[l] & 0x8000) { if (bs < NSAMP) s_idx[bs] = l; ++bs; }
        else                  { if (bu < NSAMP) s_idx[bu] = l; ++bu; }
    }
    __syncthreads();

    // --- gather + write all 4 outputs (ints written as float values) ---
    if (tid < NSAMP) {
        const int l = s_idx[tid];
        float4 bx = (l < NN) ? bb4[l] : gb4[l - NN];
        const int p = s_pk[l];
        const int c = p & 3, mi = (p >> 2) & 0xFF;
        const bool bg = (c != 1);          // background = matched_val < 0.5
        float4 gb = make_float4(0.f, 0.f, 0.f, 0.f);
        int cl = 0, si = -1;
        if (!bg) {
            gb = gb4[mi];
            cl = gtc[(size_t)b * MM + mi];
            si = mi;
        }
        const size_t rk = (size_t)b * NSAMP + tid;
        ((float4*)out)[rk] = bx;                                   // rois
        ((float4*)(out + (size_t)BB * NSAMP * 4))[rk] = gb;        // sampled_gt_boxes
        out[(size_t)2 * BB * NSAMP * 4 + rk] = (float)cl;          // classes
        out[(size_t)2 * BB * NSAMP * 4 + (size_t)BB * NSAMP + rk] = (float)si; // indices
    }
}

extern "C" void kernel_launch(void* const* d_in, const int* in_sizes, int n_in,
                              void* d_out, int out_size, void* d_ws, size_t ws_size,
                              hipStream_t stream)
{
    const float* boxes = (const float*)d_in[0];   // [32,8000,4] f32
    const float* gt    = (const float*)d_in[1];   // [32,256,4]  f32
    const int*   gtc   = (const int*)  d_in[2];   // [32,256]    i32
    const float* rnd   = (const float*)d_in[3];   // [32,8256]   f32
    float* out = (float*)d_out;
    uint32_t* keys = (uint32_t*)d_ws;             // BB*LL*SPLIT*4 = 4.22 MB
                                                  // (ws >= this: proven in R8)

    dim3 g1((LL + 511) / 512, BB, SPLIT);         // 17,32,4
    match_split_kernel<<<g1, 256, 0, stream>>>(boxes, gt, keys);
    dim3 g2((LL + 255) / 256, BB);                // 33,32
    merge2_kernel<<<g2, 256, 0, stream>>>(boxes, gt, keys);
    sample_kernel<<<BB, T2, 0, stream>>>(boxes, gt, gtc, rnd, keys, out);
}